// Round 1
// baseline (93.162 us; speedup 1.0000x reference)
//
#include <hip/hip_runtime.h>
#include <math.h>

#define NN 256
#define NF 24
#define RCUT 6.0f
#define PI_F 3.14159265358979323846f

__global__ __launch_bounds__(256) void feat_kernel(
    const float* __restrict__ Z,       // [N]
    const float* __restrict__ coords,  // [B,N,3]
    float* __restrict__ out)           // [B,N,24]
{
    const int i = blockIdx.x;
    const int b = blockIdx.y;
    const int j = threadIdx.x;

    __shared__ float xs[NN], ys[NN], zs[NN];
    __shared__ float4 geo[NN];   // dx, dy, dz, rinv  (dvec = c_i - c_j)
    __shared__ float4 wgt[NN];   // fc, eA=exp(-0.01*r2), eB=exp(-0.1*r2), r2
    __shared__ int nbr[NN];
    __shared__ int cnt;
    __shared__ float partials[4][23];

    // cooperative load of this batch's coordinates
    const float* cb = coords + (size_t)b * NN * 3;
    xs[j] = cb[j * 3 + 0];
    ys[j] = cb[j * 3 + 1];
    zs[j] = cb[j * 3 + 2];
    if (j == 0) cnt = 0;
    __syncthreads();

    const float xi = xs[i], yi = ys[i], zi = zs[i];
    const float dx = xi - xs[j], dy = yi - ys[j], dz = zi - zs[j];
    const float r2 = dx * dx + dy * dy + dz * dz;
    const float r = sqrtf(r2);
    const bool offdiag = (j != i);
    const bool incut = offdiag && (r < RCUT);
    const float fc = incut ? 0.5f * (__cosf((PI_F / RCUT) * r) + 1.0f) : 0.0f;
    const float rinv = offdiag ? (1.0f / r) : 0.0f;
    const float eA = __expf(-0.01f * r2);
    const float eB = __expf(-0.1f * r2);
    geo[j] = make_float4(dx, dy, dz, rinv);
    wgt[j] = make_float4(fc, eA, eB, r2);
    if (fc > 0.0f) { int p = atomicAdd(&cnt, 1); nbr[p] = j; }

    // 23 reduced features: [0]=sum fc, [1..4]=G2, [5..6]=G3,
    // [7..14]=G45 triple (eta,zeta,lam nested), [15..22]=G45 pair
    float acc[23];
#pragma unroll
    for (int t = 0; t < 23; t++) acc[t] = 0.0f;

    acc[0] = fc;
    acc[1] = __expf(-0.1f * r2) * fc;        // rs=0, eta=0.1
    acc[2] = __expf(-1.0f * r2) * fc;        // rs=0, eta=1.0
    {
        const float d = r - 2.0f;
        acc[3] = __expf(-0.1f * d * d) * fc; // rs=2, eta=0.1
        acc[4] = __expf(-1.0f * d * d) * fc; // rs=2, eta=1.0
    }
    acc[5] = __cosf(r) * fc;                 // kappa=1
    acc[6] = __cosf(2.0f * r) * fc;          // kappa=2

    __syncthreads();
    const int m = cnt;

    if (fc > 0.0f) {
        const float fj = fc;
        const float eAj = eA, eBj = eB;
        for (int t = 0; t < m; t++) {
            const int k = nbr[t];                 // wave-uniform -> LDS broadcast
            const float4 g = geo[k];
            const float4 w = wgt[k];
            const float ddx = dx - g.x, ddy = dy - g.y, ddz = dz - g.z;
            const float sqjk = ddx * ddx + ddy * ddy + ddz * ddz;
            const float rjk = sqrtf(sqjk);
            const float fcjk = (rjk < RCUT) ? 0.5f * (__cosf((PI_F / RCUT) * rjk) + 1.0f) : 0.0f;
            const float dot = dx * g.x + dy * g.y + dz * g.z;
            const float cost = dot * rinv * g.w;
            const float base = (k == j) ? 0.0f : fj * w.x;   // fcr_ij*fcr_ik*(j!=k)
            const float f3 = base * fcjk;
            const float f2 = base;
            const float e2a = eAj * w.y;                     // exp(-0.01*(sq_ij+sq_ik))
            const float e2b = eBj * w.z;                     // exp(-0.1 *(sq_ij+sq_ik))
            const float e3a = e2a * __expf(-0.01f * sqjk);
            const float e3b = e2b * __expf(-0.1f * sqjk);
            const float c1m = fmaxf(1.0f - cost, 0.0f);
            const float c1p = fmaxf(1.0f + cost, 0.0f);
            const float c2m = c1m * c1m, c2p = c1p * c1p;
            const float c4m = c2m * c2m, c4p = c2p * c2p;
            const float w3a = e3a * f3, w3b = e3b * f3;
            const float w2a = e2a * f2, w2b = e2b * f2;
            acc[7]  += c1m * w3a;  acc[8]  += c1p * w3a;
            acc[9]  += c4m * w3a;  acc[10] += c4p * w3a;
            acc[11] += c1m * w3b;  acc[12] += c1p * w3b;
            acc[13] += c4m * w3b;  acc[14] += c4p * w3b;
            acc[15] += c1m * w2a;  acc[16] += c1p * w2a;
            acc[17] += c4m * w2a;  acc[18] += c4p * w2a;
            acc[19] += c1m * w2b;  acc[20] += c1p * w2b;
            acc[21] += c4m * w2b;  acc[22] += c4p * w2b;
        }
    }

    // block reduction: shuffle within each wave64, then LDS across 4 waves
    const int lane = j & 63;
    const int wave = j >> 6;
#pragma unroll
    for (int t = 0; t < 23; t++) {
        float v = acc[t];
        for (int off = 32; off > 0; off >>= 1)
            v += __shfl_down(v, off, 64);
        if (lane == 0) partials[wave][t] = v;
    }
    __syncthreads();

    const size_t obase = ((size_t)b * NN + i) * NF;
    if (j < 23) {
        float v = partials[0][j] + partials[1][j] + partials[2][j] + partials[3][j];
        if (j >= 7) {
            // angular groups of 4: (z1,-),(z1,+),(z4,-),(z4,+); 2^(1-4)=0.125
            const int a = (j - 7) & 3;
            if (a >= 2) v *= 0.125f;
        }
        out[obase + 1 + j] = v;
    } else if (j == 23) {
        out[obase] = Z[i];
    }
}

extern "C" void kernel_launch(void* const* d_in, const int* in_sizes, int n_in,
                              void* d_out, int out_size, void* d_ws, size_t ws_size,
                              hipStream_t stream) {
    const float* Z = (const float*)d_in[0];       // [256]
    const float* coords = (const float*)d_in[1];  // [2,256,3]
    float* out = (float*)d_out;                   // [2,256,24]
    dim3 grid(NN, 2);
    dim3 block(NN);
    feat_kernel<<<grid, block, 0, stream>>>(Z, coords, out);
}

// Round 3
// 71.239 us; speedup vs baseline: 1.3077x; 1.3077x over previous
//
#include <hip/hip_runtime.h>
#include <math.h>

#define NN 256
#define NF 24
#define RCUT 6.0f
#define PI_F 3.14159265358979323846f
#define NSEG 2

__global__ __launch_bounds__(256) void feat_kernel(
    const float* __restrict__ Z,       // [N]
    const float* __restrict__ coords,  // [B,N,3]
    float* __restrict__ out)           // [B,N,24], pre-zeroed
{
    const int i   = blockIdx.x;
    const int b   = blockIdx.y;
    const int seg = blockIdx.z;
    const int tid = threadIdx.x;
    const int lane = tid & 63;
    const int wave = tid >> 6;

    __shared__ float4 geo[NN];   // compacted: dx, dy, dz, rinv   (dvec = c_i - c_j)
    __shared__ float4 wgt[NN];   // compacted: fc, eA=exp(-.01 r2), eB=exp(-.1 r2), 0
    __shared__ int wave_cnt[4];
    __shared__ float partials[4][23];

    const float* cb = coords + (size_t)b * NN * 3;
    const float xi = cb[i * 3 + 0], yi = cb[i * 3 + 1], zi = cb[i * 3 + 2];
    const float xj = cb[tid * 3 + 0], yj = cb[tid * 3 + 1], zj = cb[tid * 3 + 2];

    const float dx = xi - xj, dy = yi - yj, dz = zi - zj;
    const float r2 = dx * dx + dy * dy + dz * dz;
    const float r  = sqrtf(r2);
    const bool incut = (tid != i) && (r < RCUT);
    const float fc = incut ? 0.5f * (__cosf((PI_F / RCUT) * r) + 1.0f) : 0.0f;
    const float eA = __expf(-0.01f * r2);
    const float eB = __expf(-0.1f * r2);

    // deterministic compaction: ballot prefix-sum -> identical slot order in
    // both segment blocks (atomicAdd order is nondeterministic and broke the
    // cross-block pair partition in round 2)
    const unsigned long long bal = __ballot(incut);
    if (lane == 0) wave_cnt[wave] = __popcll(bal);
    __syncthreads();
    int base_slot = 0;
#pragma unroll
    for (int w = 0; w < 4; w++) if (w < wave) base_slot += wave_cnt[w];
    const int m = wave_cnt[0] + wave_cnt[1] + wave_cnt[2] + wave_cnt[3];
    if (incut) {
        const int p = base_slot + __popcll(bal & ((1ULL << lane) - 1ULL));
        geo[p] = make_float4(dx, dy, dz, 1.0f / r);
        wgt[p] = make_float4(fc, eA, eB, 0.0f);
    }

    // acc[0]=sum fc, [1..4]=G2, [5..6]=G3, [7..14]=G45 triple, [15..22]=G45 pair
    float acc[23];
#pragma unroll
    for (int t = 0; t < 23; t++) acc[t] = 0.0f;

    if (seg == 0) {  // radial features once (seg 0 only)
        acc[0] = fc;
        acc[1] = __expf(-0.1f * r2) * fc;
        acc[2] = __expf(-1.0f * r2) * fc;
        const float d = r - 2.0f;
        acc[3] = __expf(-0.1f * d * d) * fc;
        acc[4] = __expf(-1.0f * d * d) * fc;
        acc[5] = __cosf(r) * fc;
        acc[6] = __cosf(2.0f * r) * fc;
    }

    __syncthreads();

    if (tid < m) {
        const float4 gj = geo[tid];
        const float4 wj = wgt[tid];

        // round-robin unordered pairing: thread jj pairs with (jj+t)%m,
        // t=1..(m-1)/2 covers each unordered pair once; even m needs one
        // half-round at t=m/2 done by threads jj < m/2. Result x2 in epilogue.
        const int Rfull = (m - 1) >> 1;
        const int h = (Rfull + 1) >> 1;          // seg0: t in [1,h]; seg1: (h,Rfull]
        const int t0 = (seg == 0) ? 1 : h + 1;
        const int t1 = (seg == 0) ? h : Rfull;

        for (int t = t0; t <= t1; ++t) {
            int kk = tid + t; if (kk >= m) kk -= m;
            const float4 g = geo[kk];
            const float4 w = wgt[kk];
            const float ddx = gj.x - g.x, ddy = gj.y - g.y, ddz = gj.z - g.z;
            const float sqjk = ddx * ddx + ddy * ddy + ddz * ddz;
            const float rjk = sqrtf(sqjk);
            const float fcjk = (rjk < RCUT) ? 0.5f * (__cosf((PI_F / RCUT) * rjk) + 1.0f) : 0.0f;
            const float dot = gj.x * g.x + gj.y * g.y + gj.z * g.z;
            const float cost = dot * gj.w * g.w;
            const float base = wj.x * w.x;       // fcr_ij * fcr_ik
            const float f3 = base * fcjk;
            const float e2a = wj.y * w.y;        // exp(-0.01*(sq_ij+sq_ik))
            const float e2b = wj.z * w.z;
            const float e3a = e2a * __expf(-0.01f * sqjk);
            const float e3b = e2b * __expf(-0.1f * sqjk);
            const float c1m = fmaxf(1.0f - cost, 0.0f);
            const float c1p = fmaxf(1.0f + cost, 0.0f);
            const float c2m = c1m * c1m, c2p = c1p * c1p;
            const float c4m = c2m * c2m, c4p = c2p * c2p;
            const float w3a = e3a * f3, w3b = e3b * f3;
            const float w2a = e2a * base, w2b = e2b * base;
            acc[7]  += c1m * w3a;  acc[8]  += c1p * w3a;
            acc[9]  += c4m * w3a;  acc[10] += c4p * w3a;
            acc[11] += c1m * w3b;  acc[12] += c1p * w3b;
            acc[13] += c4m * w3b;  acc[14] += c4p * w3b;
            acc[15] += c1m * w2a;  acc[16] += c1p * w2a;
            acc[17] += c4m * w2a;  acc[18] += c4p * w2a;
            acc[19] += c1m * w2b;  acc[20] += c1p * w2b;
            acc[21] += c4m * w2b;  acc[22] += c4p * w2b;
        }

        if (seg == 1 && (m & 1) == 0 && tid < (m >> 1)) {
            int kk = tid + (m >> 1);
            const float4 g = geo[kk];
            const float4 w = wgt[kk];
            const float ddx = gj.x - g.x, ddy = gj.y - g.y, ddz = gj.z - g.z;
            const float sqjk = ddx * ddx + ddy * ddy + ddz * ddz;
            const float rjk = sqrtf(sqjk);
            const float fcjk = (rjk < RCUT) ? 0.5f * (__cosf((PI_F / RCUT) * rjk) + 1.0f) : 0.0f;
            const float dot = gj.x * g.x + gj.y * g.y + gj.z * g.z;
            const float cost = dot * gj.w * g.w;
            const float base = wj.x * w.x;
            const float f3 = base * fcjk;
            const float e2a = wj.y * w.y;
            const float e2b = wj.z * w.z;
            const float e3a = e2a * __expf(-0.01f * sqjk);
            const float e3b = e2b * __expf(-0.1f * sqjk);
            const float c1m = fmaxf(1.0f - cost, 0.0f);
            const float c1p = fmaxf(1.0f + cost, 0.0f);
            const float c2m = c1m * c1m, c2p = c1p * c1p;
            const float c4m = c2m * c2m, c4p = c2p * c2p;
            const float w3a = e3a * f3, w3b = e3b * f3;
            const float w2a = e2a * base, w2b = e2b * base;
            acc[7]  += c1m * w3a;  acc[8]  += c1p * w3a;
            acc[9]  += c4m * w3a;  acc[10] += c4p * w3a;
            acc[11] += c1m * w3b;  acc[12] += c1p * w3b;
            acc[13] += c4m * w3b;  acc[14] += c4p * w3b;
            acc[15] += c1m * w2a;  acc[16] += c1p * w2a;
            acc[17] += c4m * w2a;  acc[18] += c4p * w2a;
            acc[19] += c1m * w2b;  acc[20] += c1p * w2b;
            acc[21] += c4m * w2b;  acc[22] += c4p * w2b;
        }
    }

    // block reduction: shuffle within each wave64, then LDS across 4 waves
#pragma unroll
    for (int t = 0; t < 23; t++) {
        float v = acc[t];
        for (int off = 32; off > 0; off >>= 1)
            v += __shfl_down(v, off, 64);
        if (lane == 0) partials[wave][t] = v;
    }
    __syncthreads();

    const size_t obase = ((size_t)b * NN + i) * NF;
    if (tid < 23) {
        float v = partials[0][tid] + partials[1][tid] + partials[2][tid] + partials[3][tid];
        if (tid >= 7) {
            // unordered-pair x2; groups of 4: (z1,-),(z1,+),(z4,-),(z4,+); 2^(1-4)=0.125
            const int a = (tid - 7) & 3;
            v *= (a >= 2) ? 0.25f : 2.0f;
        }
        atomicAdd(&out[obase + 1 + tid], v);
    } else if (tid == 23 && seg == 0) {
        out[obase] = Z[i];
    }
}

extern "C" void kernel_launch(void* const* d_in, const int* in_sizes, int n_in,
                              void* d_out, int out_size, void* d_ws, size_t ws_size,
                              hipStream_t stream) {
    const float* Z = (const float*)d_in[0];       // [256]
    const float* coords = (const float*)d_in[1];  // [2,256,3]
    float* out = (float*)d_out;                   // [2,256,24]
    hipMemsetAsync(out, 0, (size_t)out_size * sizeof(float), stream);
    dim3 grid(NN, 2, NSEG);
    dim3 block(NN);
    feat_kernel<<<grid, block, 0, stream>>>(Z, coords, out);
}